// Round 1
// 129.194 us; speedup vs baseline: 1.0342x; 1.0342x over previous
//
#include <hip/hip_runtime.h>
#include <math.h>

#define NBINS 64
#define HIST_ELEMS (NBINS*NBINS)
#define PTS_PER_BLOCK 2304      // 384 blocks/n * 2304 = 884736 = P; grid 768 = 3/CU even
#define GXN 384                 // hist blocks per sample
#define CHUNKS 18               // per wave: 2304 / (4 waves * 32)
#define LSTRIDE 68              // col-major lh stride (b128 2-way banks = free)
// weight = exp2(-(u*SQK - b*SQK)^2); SQK = sqrt(8192/63^2*log2(e))
#define SQK 1.7256062f
#define SMEM_FLOATS (2*PTS_PER_BLOCK + NBINS*LSTRIDE)   // 8960 floats = 35840 B
#define RED_BLOCKS 128
#define TILES_PER_WAVE (GXN/4)  // 96

typedef float f4 __attribute__((ext_vector_type(4)));
typedef float f2 __attribute__((ext_vector_type(2)));
typedef float f32x4 __attribute__((ext_vector_type(4)));
typedef _Float16 half8 __attribute__((ext_vector_type(8)));
typedef int int4v __attribute__((ext_vector_type(4)));
typedef unsigned int u32x2 __attribute__((ext_vector_type(2)));

static __device__ __forceinline__ half8 pack8(const float* w) {
    int4v v;
    v[0] = __builtin_bit_cast(int, __builtin_amdgcn_cvt_pkrtz(w[0], w[1]));
    v[1] = __builtin_bit_cast(int, __builtin_amdgcn_cvt_pkrtz(w[2], w[3]));
    v[2] = __builtin_bit_cast(int, __builtin_amdgcn_cvt_pkrtz(w[4], w[5]));
    v[3] = __builtin_bit_cast(int, __builtin_amdgcn_cvt_pkrtz(w[6], w[7]));
    return __builtin_bit_cast(half8, v);
}

// packed-f32 math (gfx90a+): 2 f32 lanes per VALU issue
static __device__ __forceinline__ f2 pk_fma(f2 a, f2 b, f2 c) {
    f2 d;
    asm("v_pk_fma_f32 %0, %1, %2, %3" : "=v"(d) : "v"(a), "v"(b), "v"(c));
    return d;
}
static __device__ __forceinline__ f2 pk_mul(f2 a, f2 b) {
    f2 d;
    asm("v_pk_mul_f32 %0, %1, %2" : "=v"(d) : "v"(a), "v"(b));
    return d;
}

// ws layout: pm[512] floats @0 | unsigned ctr @2048 | float hist[2][4096] @4096
//            | _Float16 bh[2*GXN][4096] @36864
__global__ __launch_bounds__(256) void minmax_kernel(const float* __restrict__ tar,
                                                     const float* __restrict__ src,
                                                     float* __restrict__ pm,
                                                     unsigned* __restrict__ ctr,
                                                     float* __restrict__ hist, int P) {
    const int b = blockIdx.x, n = blockIdx.y, t = blockIdx.z;
    const f4* x = (const f4*)((t == 0 ? tar : src) + (size_t)n * P);
    const int per = (P / 4) / 64;   // 3456 f4 per block
    float lmin = INFINITY, lmax = -INFINITY;
    for (int i = b * per + threadIdx.x; i < (b + 1) * per; i += 256) {
        f4 v = x[i];
        lmin = fminf(lmin, fminf(fminf(v[0], v[1]), fminf(v[2], v[3])));
        lmax = fmaxf(lmax, fmaxf(fmaxf(v[0], v[1]), fmaxf(v[2], v[3])));
    }
    for (int off = 32; off > 0; off >>= 1) {
        lmin = fminf(lmin, __shfl_down(lmin, off, 64));
        lmax = fmaxf(lmax, __shfl_down(lmax, off, 64));
    }
    __shared__ float smin[4], smax[4];
    const int lane = threadIdx.x & 63, wave = threadIdx.x >> 6;
    if (lane == 0) { smin[wave] = lmin; smax[wave] = lmax; }
    __syncthreads();
    if (threadIdx.x == 0) {
        pm[(n * 2 + t) * 64 + b] =
            fminf(fminf(smin[0], smin[1]), fminf(smin[2], smin[3]));
        pm[256 + (n * 2 + t) * 64 + b] =
            fmaxf(fmaxf(smax[0], smax[1]), fmaxf(smax[2], smax[3]));
    }
    // zero global hist (8192 floats over 256 blocks = 8 f4 each) + counter
    const int flat = b + 64 * n + 128 * t;   // 0..255
    f4* hz = (f4*)hist + flat * 8;
    const f4 z = {0.f, 0.f, 0.f, 0.f};
    if (threadIdx.x < 8) hz[threadIdx.x] = z;
    if (flat == 0 && threadIdx.x == 0) *ctr = 0u;
}

// Joint histogram as 64x64xP GEMM via MFMA f16.  Wave 0 reduces the 64
// per-block minmax partials inline; one staging phase; 18 barrier-free
// K=32 chunks/wave; serial-wave NON-ATOMIC combine; private f16 bh tile
// stores.  Packed-f32 (v_pk_fma/v_pk_mul) halves non-trans VALU issues.
// A[m][k]: m=lane&15 (+16*mt), k=quad*8+j ; B[k][n]: n=lane&15, k=quad*8+j
// C/D: col=lane&15, row=quad*4+reg -> col-major lh; output TRANSPOSED
// (MI loss is transpose-invariant).
template <int STAGED>
__global__ __launch_bounds__(256) void mfma_hist_kernel(const float* __restrict__ tar,
                                                        const float* __restrict__ src,
                                                        const float* __restrict__ pm,
                                                        _Float16* __restrict__ bh,
                                                        float* __restrict__ hist,
                                                        int P) {
    const int n = blockIdx.y;
    const int bx = blockIdx.x;
    const int tid = threadIdx.x;
    const int lane = tid & 63, wave = tid >> 6;
    const int mlane = lane & 15, quad = lane >> 4;

    __shared__ float smem[SMEM_FLOATS];
    __shared__ float mmred[4];
    float* su_t = smem;
    float* su_s = smem + PTS_PER_BLOCK;
    float* lh = smem + 2 * PTS_PER_BLOCK;   // col-major: lh[col*LSTRIDE + row]

    // --- wave 0: reduce the 64 per-block minmax partials ---
    if (wave == 0) {
        float a = pm[(n * 2 + 0) * 64 + lane];
        float b = pm[256 + (n * 2 + 0) * 64 + lane];
        float c = pm[(n * 2 + 1) * 64 + lane];
        float d = pm[256 + (n * 2 + 1) * 64 + lane];
        for (int off = 32; off > 0; off >>= 1) {
            a = fminf(a, __shfl_down(a, off, 64));
            b = fmaxf(b, __shfl_down(b, off, 64));
            c = fminf(c, __shfl_down(c, off, 64));
            d = fmaxf(d, __shfl_down(d, off, 64));
        }
        if (lane == 0) { mmred[0] = a; mmred[1] = b; mmred[2] = c; mmred[3] = d; }
    }

    // --- stage raw inputs: 576 f4 per tensor, coalesced ---
    {
        const f4* tg = (const f4*)(tar + (size_t)n * P + (size_t)bx * PTS_PER_BLOCK);
        const f4* sg = (const f4*)(src + (size_t)n * P + (size_t)bx * PTS_PER_BLOCK);
        f4* st4 = (f4*)su_t;
        f4* ss4 = (f4*)su_s;
        #pragma unroll
        for (int k = 0; k < 2; ++k) {
            const int i = tid + k * 256;
            st4[i] = tg[i];
            ss4[i] = sg[i];
        }
        if (tid < 64) {
            const int i = 512 + tid;
            st4[i] = tg[i];
            ss4[i] = sg[i];
        }
    }
    __syncthreads();   // staging + mmred complete

    const float tmin = mmred[0], tmax = mmred[1];
    const float smin = mmred[2], smax = mmred[3];
    const float tk = 63.0f / (tmax - tmin + 1e-10f) * SQK;
    const float sk = 63.0f / (smax - smin + 1e-10f) * SQK;
    const f2 tkk = {tk, tk}, skk = {sk, sk};
    f2 tneg[4], sneg[4];
    #pragma unroll
    for (int mt = 0; mt < 4; ++mt) {
        const float b = SQK * (float)(mlane + 16 * mt);
        const float tb_ = tmin * tk + b;
        const float sb_ = smin * sk + b;
        tneg[mt] = {-tb_, -tb_};
        sneg[mt] = {-sb_, -sb_};
    }

    f32x4 acc[4][4];
    #pragma unroll
    for (int a = 0; a < 4; ++a)
        #pragma unroll
        for (int b = 0; b < 4; ++b) acc[a][b] = (f32x4){0.f, 0.f, 0.f, 0.f};

    // --- compute: wave owns 576 points = 18 chunks of K=32, barrier-free ---
    const int kwbase = wave * (32 * CHUNKS) + quad * 8;
    #pragma unroll 3
    for (int c = 0; c < CHUNKS; ++c) {
        const int kbase = kwbase + c * 32;
        const f4* pt4 = (const f4*)&su_t[kbase];
        const f4* ps4 = (const f4*)&su_s[kbase];
        f4 ta = pt4[0], tb = pt4[1];
        f4 sa = ps4[0], sb = ps4[1];
        f2 tp[4], sp[4];
        tp[0] = {ta[0], ta[1]}; tp[1] = {ta[2], ta[3]};
        tp[2] = {tb[0], tb[1]}; tp[3] = {tb[2], tb[3]};
        sp[0] = {sa[0], sa[1]}; sp[1] = {sa[2], sa[3]};
        sp[2] = {sb[0], sb[1]}; sp[3] = {sb[2], sb[3]};

        half8 af[4], bf[4];
        #pragma unroll
        for (int mt = 0; mt < 4; ++mt) {
            float w[8];
            #pragma unroll
            for (int h = 0; h < 4; ++h) {
                f2 d = pk_fma(tp[h], tkk, tneg[mt]);
                f2 s2 = pk_mul(d, d);
                w[2 * h]     = __builtin_amdgcn_exp2f(-s2[0]);
                w[2 * h + 1] = __builtin_amdgcn_exp2f(-s2[1]);
            }
            af[mt] = pack8(w);
        }
        #pragma unroll
        for (int nt = 0; nt < 4; ++nt) {
            float w[8];
            #pragma unroll
            for (int h = 0; h < 4; ++h) {
                f2 d = pk_fma(sp[h], skk, sneg[nt]);
                f2 s2 = pk_mul(d, d);
                w[2 * h]     = __builtin_amdgcn_exp2f(-s2[0]);
                w[2 * h + 1] = __builtin_amdgcn_exp2f(-s2[1]);
            }
            bf[nt] = pack8(w);
        }
        #pragma unroll
        for (int mt = 0; mt < 4; ++mt)
            #pragma unroll
            for (int nt = 0; nt < 4; ++nt)
                acc[mt][nt] = __builtin_amdgcn_mfma_f32_16x16x32_f16(
                    af[mt], bf[nt], acc[mt][nt], 0, 0, 0);
    }

    // --- serial-wave non-atomic combine into col-major lh ---
    #pragma unroll
    for (int w = 0; w < 4; ++w) {
        if (wave == w) {
            #pragma unroll
            for (int nt = 0; nt < 4; ++nt)
                #pragma unroll
                for (int mt = 0; mt < 4; ++mt) {
                    f4* p = (f4*)&lh[(16 * nt + mlane) * LSTRIDE + 16 * mt + 4 * quad];
                    if (w == 0) {
                        *p = acc[mt][nt];
                    } else {
                        f4 v = *p;
                        v += acc[mt][nt];
                        *p = v;
                    }
                }
        }
        __syncthreads();
    }

    if (STAGED) {
        // compact col-major lh -> private dense 4096-entry f16 tile (no atomics)
        u32x2* dst = (u32x2*)(bh + ((size_t)n * GXN + bx) * HIST_ELEMS);
        #pragma unroll
        for (int k = 0; k < 4; ++k) {
            const int i4 = tid + k * 256;          // 0..1023, 4 f16 each
            const int c = i4 >> 4, r4 = (i4 & 15) * 4;
            f4 v = *(const f4*)&lh[c * LSTRIDE + r4];
            u32x2 o;
            o[0] = __builtin_bit_cast(unsigned int, __builtin_amdgcn_cvt_pkrtz(v[0], v[1]));
            o[1] = __builtin_bit_cast(unsigned int, __builtin_amdgcn_cvt_pkrtz(v[2], v[3]));
            dst[i4] = o;
        }
    } else {
        float* gh = hist + (size_t)n * HIST_ELEMS;
        for (int i = tid; i < HIST_ELEMS; i += 256) {
            const int c = i >> 6, r = i & 63;
            unsafeAtomicAdd(&gh[i], lh[c * LSTRIDE + r]);
        }
    }
}

// 128 blocks: each owns 64 hist elements; each wave sums 96 f16 tiles,
// LDS-combine, plain store -> hist.  Last-arriving block finalizes.
__global__ __launch_bounds__(256) void reduce_finalize_kernel(const _Float16* __restrict__ bh,
                                                              float* __restrict__ hist,
                                                              unsigned* __restrict__ ctr,
                                                              float* __restrict__ out,
                                                              int staged) {
    const int tid = threadIdx.x;
    const int lane = tid & 63, wave = tid >> 6;
    __shared__ float h2[2 * HIST_ELEMS];
    __shared__ float buf[4], rowsum[NBINS], colsum[NBINS], colp[4 * NBINS];
    __shared__ float part[4][64];
    __shared__ int lastflag;

    if (staged) {
        const int g = blockIdx.x * 64 + lane;   // 0..8191
        const int n = g >> 12, e = g & 4095;
        const _Float16* p = bh + (((size_t)(n * GXN + wave * TILES_PER_WAVE)) << 12) + e;
        float s = 0.0f;
        #pragma unroll 8
        for (int b = 0; b < TILES_PER_WAVE; ++b) s += (float)p[(size_t)b << 12];
        part[wave][lane] = s;
        __syncthreads();
        if (wave == 0)
            hist[g] = part[0][lane] + part[1][lane] + part[2][lane] + part[3][lane];
    }

    __threadfence();
    if (tid == 0) {
        unsigned old = atomicAdd(ctr, 1u);
        lastflag = (old == RED_BLOCKS - 1) ? 1 : 0;
    }
    __syncthreads();
    if (!lastflag) return;

    // system-scope loads: bypass per-XCD L2 (writers fenced via threadfence)
    for (int i = tid; i < 2 * HIST_ELEMS; i += 256)
        h2[i] = __hip_atomic_load(&hist[i], __ATOMIC_RELAXED, __HIP_MEMORY_SCOPE_SYSTEM);
    __syncthreads();

    float accl = 0.0f;
    for (int nn = 0; nn < 2; ++nn) {
        const float* h = h2 + nn * HIST_ELEMS;
        {
            int r = tid >> 2, q = tid & 3;
            const float* hp = h + r * NBINS + q * 16;
            float sv = 0.0f;
            #pragma unroll
            for (int k = 0; k < 16; ++k) sv += hp[k];
            sv += __shfl_down(sv, 1, 64);
            sv += __shfl_down(sv, 2, 64);
            if (q == 0) rowsum[r] = sv;
        }
        {
            int c = tid & 63, g = tid >> 6;
            const float* hp = h + (g * 16) * NBINS + c;
            float sv = 0.0f;
            #pragma unroll
            for (int k = 0; k < 16; ++k) sv += hp[k * NBINS];
            colp[g * NBINS + c] = sv;
        }
        __syncthreads();
        if (tid < NBINS)
            colsum[tid] = colp[0 * NBINS + tid] + colp[1 * NBINS + tid] +
                          colp[2 * NBINS + tid] + colp[3 * NBINS + tid];
        __syncthreads();

        float tv = (tid < NBINS) ? rowsum[tid] : 0.0f;
        for (int off = 32; off > 0; off >>= 1) tv += __shfl_down(tv, off, 64);
        __syncthreads();
        if (lane == 0) buf[wave] = tv;
        __syncthreads();
        const float total = buf[0] + buf[1] + buf[2] + buf[3];
        const float inv = 1.0f / total;

        float ej = 0.0f;
        for (int i = tid; i < HIST_ELEMS; i += 256) {
            float p = h[i] * inv;
            ej += p * __logf(p + 1e-10f);
        }
        for (int off = 32; off > 0; off >>= 1) ej += __shfl_down(ej, off, 64);
        __syncthreads();
        if (lane == 0) buf[wave] = ej;
        __syncthreads();
        const float entj = -(buf[0] + buf[1] + buf[2] + buf[3]);

        float em = 0.0f;
        if (tid < NBINS) {
            float p = rowsum[tid] * inv;
            em = p * __logf(p + 1e-10f);
        } else if (tid < 2 * NBINS) {
            float p = colsum[tid - NBINS] * inv;
            em = p * __logf(p + 1e-10f);
        }
        for (int off = 32; off > 0; off >>= 1) em += __shfl_down(em, off, 64);
        __syncthreads();
        if (lane == 0) buf[wave] = em;
        __syncthreads();
        const float ents = -(buf[0] + buf[1] + buf[2] + buf[3]);

        accl += ents / entj;
        __syncthreads();
    }
    if (tid == 0) out[0] = -0.5f * accl;
}

extern "C" void kernel_launch(void* const* d_in, const int* in_sizes, int n_in,
                              void* d_out, int out_size, void* d_ws, size_t ws_size,
                              hipStream_t stream) {
    const float* tar = (const float*)d_in[0];
    const float* src = (const float*)d_in[1];
    const int N = 2;
    const int P = in_sizes[0] / N;  // 884736

    float* pm = (float*)d_ws;
    unsigned* ctr = (unsigned*)((char*)d_ws + 2048);
    float* hist = (float*)((char*)d_ws + 4096);
    _Float16* bh = (_Float16*)((char*)d_ws + 36864);
    float* out = (float*)d_out;

    const size_t need = 36864 + (size_t)2 * GXN * HIST_ELEMS * sizeof(_Float16); // ~6.33 MB

    minmax_kernel<<<dim3(64, N, 2), 256, 0, stream>>>(tar, src, pm, ctr, hist, P);
    if (ws_size >= need) {
        mfma_hist_kernel<1><<<dim3(GXN, N), 256, 0, stream>>>(tar, src, pm, bh, hist, P);
        reduce_finalize_kernel<<<RED_BLOCKS, 256, 0, stream>>>(bh, hist, ctr, out, 1);
    } else {
        mfma_hist_kernel<0><<<dim3(GXN, N), 256, 0, stream>>>(tar, src, pm, bh, hist, P);
        reduce_finalize_kernel<<<RED_BLOCKS, 256, 0, stream>>>(bh, hist, ctr, out, 0);
    }
}